// Round 1
// baseline (86.170 us; speedup 1.0000x reference)
//
#include <hip/hip_runtime.h>

// CenterLoss, exact masked shortcut:
//   out = mean_i clip(0.5*(||x_i||^2 + ||c_{l_i}||^2) + 0.3 * x_i . c_{l_i}, 1e-12, 1e12)
//         + (C-1)*1e-12          // the B*(C-1) masked-out zeros, each clipped to 1e-12
// B=4096, C=10000, D=512 (fp32 inputs, int32 labels, fp32 scalar output)

constexpr int BATCH = 4096;
constexpr int NCLASS = 10000;
constexpr int DIM = 512;

// One wave (64 lanes) per row. 256-thread blocks -> 4 rows/block -> 1024 blocks.
__global__ __launch_bounds__(256) void center_loss_rows(
    const float* __restrict__ x,
    const float* __restrict__ centers,
    const int* __restrict__ labels,
    double* __restrict__ accum) {
  const int row  = (int)((blockIdx.x * blockDim.x + threadIdx.x) >> 6);
  const int lane = (int)(threadIdx.x & 63);
  const int widx = (int)(threadIdx.x >> 6);  // wave index within block (0..3)

  __shared__ float wave_val[4];

  float s = 0.0f;
  if (row < BATCH) {
    const int lbl = labels[row];
    const float* __restrict__ xr = x + (size_t)row * DIM;
    const float* __restrict__ cr = centers + (size_t)lbl * DIM;

    float xx = 0.0f, cc = 0.0f, xc = 0.0f;
    // 512 floats / 64 lanes = 8 floats/lane = two float4 chunks, coalesced.
#pragma unroll
    for (int k = 0; k < 2; ++k) {
      const int off = k * 256 + lane * 4;
      const float4 xv = *(const float4*)(xr + off);
      const float4 cv = *(const float4*)(cr + off);
      xx += xv.x * xv.x + xv.y * xv.y + xv.z * xv.z + xv.w * xv.w;
      cc += cv.x * cv.x + cv.y * cv.y + cv.z * cv.z + cv.w * cv.w;
      xc += xv.x * cv.x + xv.y * cv.y + xv.z * cv.z + xv.w * cv.w;
    }
    // 64-lane butterfly reduction.
#pragma unroll
    for (int sh = 32; sh > 0; sh >>= 1) {
      xx += __shfl_down(xx, sh, 64);
      cc += __shfl_down(cc, sh, 64);
      xc += __shfl_down(xc, sh, 64);
    }
    s = 0.5f * (xx + cc) + 0.3f * xc;
    // clamp AFTER masking, faithful to reference
    s = fminf(fmaxf(s, 1e-12f), 1e12f);
  }

  if (lane == 0) wave_val[widx] = s;
  __syncthreads();
  if (threadIdx.x == 0) {
    const double blk = (double)wave_val[0] + (double)wave_val[1] +
                       (double)wave_val[2] + (double)wave_val[3];
    atomicAdd(accum, blk);  // fp64 global atomic: native on gfx90a+/gfx950
  }
}

__global__ void center_loss_finalize(const double* __restrict__ accum,
                                     float* __restrict__ out) {
  // B*(C-1) zeroed entries each clip to 1e-12; divide total by B.
  const double total = accum[0] + (double)BATCH * (double)(NCLASS - 1) * 1e-12;
  out[0] = (float)(total / (double)BATCH);
}

extern "C" void kernel_launch(void* const* d_in, const int* in_sizes, int n_in,
                              void* d_out, int out_size, void* d_ws, size_t ws_size,
                              hipStream_t stream) {
  const float* x       = (const float*)d_in[0];
  const float* centers = (const float*)d_in[1];
  const int*   labels  = (const int*)d_in[2];
  float*       out     = (float*)d_out;
  double*      accum   = (double*)d_ws;

  // d_ws is poisoned 0xAA before every timed launch — zero our 8-byte accumulator.
  hipMemsetAsync(accum, 0, sizeof(double), stream);

  const int threads = 256;
  const int rows_per_block = threads / 64;
  const int blocks = (BATCH + rows_per_block - 1) / rows_per_block;  // 1024
  center_loss_rows<<<blocks, threads, 0, stream>>>(x, centers, labels, accum);
  center_loss_finalize<<<1, 1, 0, stream>>>(accum, out);
}

// Round 2
// 73.326 us; speedup vs baseline: 1.1752x; 1.1752x over previous
//
#include <hip/hip_runtime.h>

// CenterLoss, exact masked shortcut:
//   out = mean_i clip(0.5*(||x_i||^2 + ||c_{l_i}||^2) + 0.3 * x_i . c_{l_i}, 1e-12, 1e12)
//         + (C-1)*1e-12          // the B*(C-1) masked-out zeros, each clipped to 1e-12
// B=4096, C=10000, D=512 (fp32 inputs, int32 labels, fp32 scalar output)
//
// Structure: 2 graph nodes, zero initialization requirements.
//   k1: 1024 blocks x 256 thr, 1 wave per row -> partial[blockIdx] (plain store,
//       overwrites the 0xAA poison, no memset needed)
//   k2: 1 block, 256 thr, reduces 1024 partials -> out scalar
// Round-1 evidence: dur_us is dominated by the harness's 2x256MiB d_ws poison
// fills (44 us each @ 76% HBM peak); our job is just to not add overhead.

constexpr int BATCH = 4096;
constexpr int NCLASS = 10000;
constexpr int DIM = 512;
constexpr int ROWS_PER_BLOCK = 4;                    // 4 waves/block
constexpr int NBLOCKS = BATCH / ROWS_PER_BLOCK;      // 1024

__global__ __launch_bounds__(256) void center_loss_rows(
    const float* __restrict__ x,
    const float* __restrict__ centers,
    const int* __restrict__ labels,
    double* __restrict__ partial) {
  const int row  = (int)(blockIdx.x * ROWS_PER_BLOCK + (threadIdx.x >> 6));
  const int lane = (int)(threadIdx.x & 63);
  const int widx = (int)(threadIdx.x >> 6);

  __shared__ float wave_val[ROWS_PER_BLOCK];

  const int lbl = labels[row];
  const float* __restrict__ xr = x + (size_t)row * DIM;
  const float* __restrict__ cr = centers + (size_t)lbl * DIM;

  float xx = 0.0f, cc = 0.0f, xc = 0.0f;
  // 512 floats / 64 lanes = 8 floats/lane = two float4 chunks, coalesced.
#pragma unroll
  for (int k = 0; k < 2; ++k) {
    const int off = k * 256 + lane * 4;
    const float4 xv = *(const float4*)(xr + off);
    const float4 cv = *(const float4*)(cr + off);
    xx += xv.x * xv.x + xv.y * xv.y + xv.z * xv.z + xv.w * xv.w;
    cc += cv.x * cv.x + cv.y * cv.y + cv.z * cv.z + cv.w * cv.w;
    xc += xv.x * cv.x + xv.y * cv.y + xv.z * cv.z + xv.w * cv.w;
  }
#pragma unroll
  for (int sh = 32; sh > 0; sh >>= 1) {
    xx += __shfl_down(xx, sh, 64);
    cc += __shfl_down(cc, sh, 64);
    xc += __shfl_down(xc, sh, 64);
  }
  float s = 0.5f * (xx + cc) + 0.3f * xc;
  s = fminf(fmaxf(s, 1e-12f), 1e12f);   // clamp AFTER masking, faithful

  if (lane == 0) wave_val[widx] = s;
  __syncthreads();
  if (threadIdx.x == 0) {
    partial[blockIdx.x] = (double)wave_val[0] + (double)wave_val[1] +
                          (double)wave_val[2] + (double)wave_val[3];
  }
}

__global__ __launch_bounds__(256) void center_loss_reduce(
    const double* __restrict__ partial,
    float* __restrict__ out) {
  const int tid  = (int)threadIdx.x;
  const int lane = tid & 63;
  const int widx = tid >> 6;

  __shared__ double wave_sum[4];

  // 1024 partials / 256 threads = 4 each
  double s = partial[tid] + partial[tid + 256] +
             partial[tid + 512] + partial[tid + 768];
#pragma unroll
  for (int sh = 32; sh > 0; sh >>= 1) {
    s += __shfl_down(s, sh, 64);
  }
  if (lane == 0) wave_sum[widx] = s;
  __syncthreads();
  if (tid == 0) {
    double total = wave_sum[0] + wave_sum[1] + wave_sum[2] + wave_sum[3];
    total += (double)BATCH * (double)(NCLASS - 1) * 1e-12;  // clipped zeros
    out[0] = (float)(total / (double)BATCH);
  }
}

extern "C" void kernel_launch(void* const* d_in, const int* in_sizes, int n_in,
                              void* d_out, int out_size, void* d_ws, size_t ws_size,
                              hipStream_t stream) {
  const float* x       = (const float*)d_in[0];
  const float* centers = (const float*)d_in[1];
  const int*   labels  = (const int*)d_in[2];
  float*       out     = (float*)d_out;
  double*      partial = (double*)d_ws;   // 1024 doubles = 8 KB of ws

  center_loss_rows<<<NBLOCKS, 256, 0, stream>>>(x, centers, labels, partial);
  center_loss_reduce<<<1, 256, 0, stream>>>(partial, out);
}